// Round 3
// baseline (87.250 us; speedup 1.0000x reference)
//
#include <hip/hip_runtime.h>

#define L1V 1444
#define LTOT 1768
#define CRV 32
#define CHV 64
#define HWV 1600

// ---------------- K1: base = prelu(w1·x), wf = prelu(w2·avgpool(x)), global sumsq ----------------
__global__ __launch_bounds__(256) void k_front(const float* __restrict__ x,
    const float* __restrict__ w1, const float* __restrict__ b1, const float* __restrict__ a1,
    const float* __restrict__ w2, const float* __restrict__ b2, const float* __restrict__ a2,
    float* __restrict__ base, float* __restrict__ wf, float* __restrict__ sumsq)
{
    int t = blockIdx.x * 256 + threadIdx.x;
    float sq = 0.f;
    if (t < CRV * HWV) {                      // blocks 0..199: base
        int c = t / HWV, px = t - c * HWV;
        float acc = b1[c];
        #pragma unroll 8
        for (int ic = 0; ic < CHV; ++ic) acc += w1[c * CHV + ic] * x[ic * HWV + px];
        float a = a1[0];
        float v = acc >= 0.f ? acc : a * acc;
        base[t] = v;
        sq = v * v;
    } else {                                   // blocks 200..249: wf
        int u = t - CRV * HWV;                 // < 12800
        int c = u / 400, p = u - c * 400;
        int i = p / 20, j = p - i * 20;
        int px0 = (2 * i) * 40 + 2 * j;
        float acc = b2[c];
        for (int ic = 0; ic < CHV; ++ic) {
            const float* xp = x + ic * HWV + px0;
            float xd = 0.25f * (xp[0] + xp[1] + xp[40] + xp[41]);
            acc += w2[c * CHV + ic] * xd;
        }
        float a = a2[0];
        float v = acc >= 0.f ? acc : a * acc;
        wf[u] = v;
        sq = v * v;
    }
    __shared__ float red[256];
    red[threadIdx.x] = sq;
    __syncthreads();
    for (int s = 128; s > 0; s >>= 1) {
        if (threadIdx.x < s) red[threadIdx.x] += red[threadIdx.x + s];
        __syncthreads();
    }
    if (threadIdx.x == 0) atomicAdd(&sumsq[blockIdx.x < 200 ? 0 : 1], red[0]);
}

// ---------------- K2: fused per-channel patch attention ----------------
// grid = (8 query-tiles of 192, 32 channels) = 256 blocks (1 per CU).
// block = 512 threads (8 waves). Each lane owns Q=3 queries (m, m+64, m+128);
// wave w handles l-segment [w*221, w*221+221). pan staged in LDS as
// float4 x2 + float per l. SCALE*log2e folded into q registers; native exp2.
// __launch_bounds__(512, 2): 2 waves/EU -> VGPR cap 256, keeps q/num/den
// (57+ floats) fully in registers. Occupancy is LDS-bound anyway (64KB/block).
__global__ __launch_bounds__(512, 2) void k_attn(const float* __restrict__ base,
    const float* __restrict__ wf, const float* __restrict__ sumsq,
    float* __restrict__ patches)
{
    __shared__ __align__(16) float lds[15912];   // 63,648 B
    float* panA = lds;                            // [1768][4] k=0..3
    float* panB = lds + 7072;                     // [1768][4] k=4..7
    float* panC = lds + 14144;                    // [1768]    k=8
    const int c   = blockIdx.y;
    const int qb  = blockIdx.x;
    const int tid = threadIdx.x;
    const float bmax = sqrtf(sumsq[0]);
    const float wmax = sqrtf(sumsq[1]);
    const float invb = 1.0f / bmax, invw = 1.0f / wmax;

    // stage pan: one l per thread per iteration
    for (int l = tid; l < LTOT; l += 512) {
        const float* src;
        int stride;
        float scale;
        if (l < L1V) {
            int i = l / 38, j = l - i * 38;
            src = base + c * HWV + i * 40 + j;
            stride = 40; scale = invb;
        } else {
            int l2 = l - L1V;
            int i = l2 / 18, j = l2 - i * 18;
            src = wf + c * 400 + i * 20 + j;
            stride = 20; scale = invw;
        }
        float v0 = src[0]          * scale, v1 = src[1]          * scale, v2 = src[2]          * scale;
        float v3 = src[stride]     * scale, v4 = src[stride+1]   * scale, v5 = src[stride+2]   * scale;
        float v6 = src[2*stride]   * scale, v7 = src[2*stride+1] * scale, v8 = src[2*stride+2] * scale;
        *reinterpret_cast<float4*>(&panA[l*4]) = make_float4(v0, v1, v2, v3);
        *reinterpret_cast<float4*>(&panB[l*4]) = make_float4(v4, v5, v6, v7);
        panC[l] = v8;
    }
    __syncthreads();

    const int lane = tid & 63;
    const int w    = tid >> 6;                 // 0..7 : l-segment
    const float SC = 10.0f * 1.44269504088896f;

    // load Q=3 query vectors, pre-scaled by SCALE*log2(e)
    float q[3][9];
    #pragma unroll
    for (int qi = 0; qi < 3; ++qi) {
        int m = qb * 192 + qi * 64 + lane;     // < 1536 <= 1768, always safe to read
        #pragma unroll
        for (int k = 0; k < 4; ++k) q[qi][k]   = panA[m*4+k] * SC;
        #pragma unroll
        for (int k = 0; k < 4; ++k) q[qi][4+k] = panB[m*4+k] * SC;
        q[qi][8] = panC[m] * SC;
    }

    float num[3][9];
    float den[3] = {0.f, 0.f, 0.f};
    #pragma unroll
    for (int qi = 0; qi < 3; ++qi)
        #pragma unroll
        for (int k = 0; k < 9; ++k) num[qi][k] = 0.f;

    const int l0 = w * 221, l1e = l0 + 221;

    #define ATTN_ITER(VS)                                                     \
    {                                                                         \
        float4 A  = *reinterpret_cast<const float4*>(&panA[l*4]);             \
        float4 Bv = *reinterpret_cast<const float4*>(&panB[l*4]);             \
        float  c8 = panC[l];                                                  \
        _Pragma("unroll")                                                     \
        for (int qi = 0; qi < 3; ++qi) {                                      \
            float s = q[qi][0]*A.x + q[qi][1]*A.y + q[qi][2]*A.z + q[qi][3]*A.w \
                    + q[qi][4]*Bv.x + q[qi][5]*Bv.y + q[qi][6]*Bv.z + q[qi][7]*Bv.w \
                    + q[qi][8]*c8;                                            \
            float p  = __builtin_amdgcn_exp2f(s);                             \
            float pv = p * (VS);                                              \
            den[qi] += p;                                                     \
            num[qi][0] += pv*A.x;  num[qi][1] += pv*A.y;                      \
            num[qi][2] += pv*A.z;  num[qi][3] += pv*A.w;                      \
            num[qi][4] += pv*Bv.x; num[qi][5] += pv*Bv.y;                     \
            num[qi][6] += pv*Bv.z; num[qi][7] += pv*Bv.w;                     \
            num[qi][8] += pv*c8;                                              \
        }                                                                     \
    }

    const int e1 = (l1e < L1V) ? l1e : L1V;    // base-segment end for this wave
    #pragma unroll 2
    for (int l = l0; l < e1; ++l) ATTN_ITER(bmax)
    const int s2 = (l0 > L1V) ? l0 : L1V;      // w-segment start for this wave
    #pragma unroll 2
    for (int l = s2; l < l1e; ++l) ATTN_ITER(wmax)
    #undef ATTN_ITER

    __syncthreads();                 // pan no longer needed; overlay partials
    float* part = lds;               // [8 waves][192 q][10] = 61,440 B
    #pragma unroll
    for (int qi = 0; qi < 3; ++qi) {
        float* myp = part + (w * 192 + qi * 64 + lane) * 10;
        #pragma unroll
        for (int k = 0; k < 9; ++k) myp[k] = num[qi][k];
        myp[9] = den[qi];
    }
    __syncthreads();

    if (tid < 192) {
        int m = qb * 192 + tid;
        if (m < L1V) {
            float tot[10];
            #pragma unroll
            for (int j = 0; j < 10; ++j) {
                float s = 0.f;
                #pragma unroll
                for (int ww = 0; ww < 8; ++ww) s += part[(ww * 192 + tid) * 10 + j];
                tot[j] = s;
            }
            float inv = 1.0f / tot[9];
            #pragma unroll
            for (int k = 0; k < 9; ++k)
                patches[(c * 9 + k) * L1V + m] = tot[k] * inv;
        }
    }
}

// ---------------- K3: fold (sum overlapping patches) / 9 ----------------
__global__ __launch_bounds__(256) void k_fold(const float* __restrict__ patches,
                                              float* __restrict__ folded)
{
    int t = blockIdx.x * 256 + threadIdx.x;
    if (t >= CRV * HWV) return;
    int c = t / HWV, px = t - c * HWV;
    int h = px / 40, w = px - h * 40;
    float acc = 0.f;
    #pragma unroll
    for (int di = 0; di < 3; ++di) {
        int i = h - di;
        if (i < 0 || i >= 38) continue;
        #pragma unroll
        for (int dj = 0; dj < 3; ++dj) {
            int j = w - dj;
            if (j < 0 || j >= 38) continue;
            acc += patches[(c * 9 + di * 3 + dj) * L1V + i * 38 + j];
        }
    }
    folded[t] = acc * (1.0f / 9.0f);
}

// ---------------- K4: y = prelu(w3·folded + b3) + x ----------------
__global__ __launch_bounds__(256) void k_out(const float* __restrict__ folded,
    const float* __restrict__ w3, const float* __restrict__ b3, const float* __restrict__ a3,
    const float* __restrict__ x, float* __restrict__ out)
{
    int t = blockIdx.x * 256 + threadIdx.x;
    if (t >= CHV * HWV) return;
    int oc = t / HWV, px = t - oc * HWV;
    float acc = b3[oc];
    #pragma unroll
    for (int ic = 0; ic < CRV; ++ic) acc += w3[oc * CRV + ic] * folded[ic * HWV + px];
    float a = a3[0];
    float v = acc >= 0.f ? acc : a * acc;
    out[t] = v + x[t];
}

extern "C" void kernel_launch(void* const* d_in, const int* in_sizes, int n_in,
                              void* d_out, int out_size, void* d_ws, size_t ws_size,
                              hipStream_t stream)
{
    const float* x  = (const float*)d_in[0];
    const float* w1 = (const float*)d_in[1];
    const float* b1 = (const float*)d_in[2];
    const float* a1 = (const float*)d_in[3];
    const float* w2 = (const float*)d_in[4];
    const float* b2 = (const float*)d_in[5];
    const float* a2 = (const float*)d_in[6];
    const float* w3 = (const float*)d_in[7];
    const float* b3 = (const float*)d_in[8];
    const float* a3 = (const float*)d_in[9];

    float* ws      = (float*)d_ws;
    float* sumsq   = ws;                               // 2 floats (+pad to 64)
    float* base    = ws + 64;                          // 32*1600 = 51200
    float* wfb     = base + CRV * HWV;                 // 32*400  = 12800
    float* patches = wfb + 12800;                      // 32*9*1444 = 415872
    float* folded  = patches + CRV * 9 * L1V;          // 51200

    hipMemsetAsync(sumsq, 0, 2 * sizeof(float), stream);
    k_front<<<250, 256, 0, stream>>>(x, w1, b1, a1, w2, b2, a2, base, wfb, sumsq);
    k_attn<<<dim3(8, 32), 512, 0, stream>>>(base, wfb, sumsq, patches);
    k_fold<<<200, 256, 0, stream>>>(patches, folded);
    k_out<<<400, 256, 0, stream>>>(folded, w3, b3, a3, x, (float*)d_out);
}

// Round 4
// 78.925 us; speedup vs baseline: 1.1055x; 1.1055x over previous
//
#include <hip/hip_runtime.h>

#define L1V 1444
#define LTOT 1768
#define LHALF 884
#define LB1 560          // within half 1: l_local 560 <=> global l 1444 (base/wf boundary)
#define CRV 32
#define CHV 64
#define HWV 1600

// ---------------- K1: base = prelu(w1·x), wf = prelu(w2·avgpool(x)), global sumsq ----------------
__global__ __launch_bounds__(256) void k_front(const float* __restrict__ x,
    const float* __restrict__ w1, const float* __restrict__ b1, const float* __restrict__ a1,
    const float* __restrict__ w2, const float* __restrict__ b2, const float* __restrict__ a2,
    float* __restrict__ base, float* __restrict__ wf, float* __restrict__ sumsq)
{
    int t = blockIdx.x * 256 + threadIdx.x;
    float sq = 0.f;
    if (t < CRV * HWV) {                      // blocks 0..199: base
        int c = t / HWV, px = t - c * HWV;
        float acc = b1[c];
        #pragma unroll 8
        for (int ic = 0; ic < CHV; ++ic) acc += w1[c * CHV + ic] * x[ic * HWV + px];
        float a = a1[0];
        float v = acc >= 0.f ? acc : a * acc;
        base[t] = v;
        sq = v * v;
    } else {                                   // blocks 200..249: wf
        int u = t - CRV * HWV;                 // < 12800
        int c = u / 400, p = u - c * 400;
        int i = p / 20, j = p - i * 20;
        int px0 = (2 * i) * 40 + 2 * j;
        float acc = b2[c];
        for (int ic = 0; ic < CHV; ++ic) {
            const float* xp = x + ic * HWV + px0;
            float xd = 0.25f * (xp[0] + xp[1] + xp[40] + xp[41]);
            acc += w2[c * CHV + ic] * xd;
        }
        float a = a2[0];
        float v = acc >= 0.f ? acc : a * acc;
        wf[u] = v;
        sq = v * v;
    }
    __shared__ float red[256];
    red[threadIdx.x] = sq;
    __syncthreads();
    for (int s = 128; s > 0; s >>= 1) {
        if (threadIdx.x < s) red[threadIdx.x] += red[threadIdx.x + s];
        __syncthreads();
    }
    if (threadIdx.x == 0) atomicAdd(&sumsq[blockIdx.x < 200 ? 0 : 1], red[0]);
}

// ---------------- K2: fused per-channel patch attention, key-split ----------------
// grid = (8 qtiles x 32 channels x 2 key-halves) = 512 blocks = 2 blocks/CU
// -> 16 waves/CU = 4 waves/SIMD (latency hiding; R3 was 1 block/CU = 2/SIMD).
// block = 512 thr (8 waves). Lane owns Q=3 queries (loaded from global);
// wave w handles ~110 keys of this block's 884-key half (staged in LDS).
// Partial num[9]/den per (query, half) -> ws; k_comb merges and divides.
__global__ __launch_bounds__(512, 2) void k_attn(const float* __restrict__ base,
    const float* __restrict__ wf, const float* __restrict__ sumsq,
    float* __restrict__ part)
{
    __shared__ __align__(16) float lds[15360];   // 61,440 B (reduction overlay needs it)
    float* panA = lds;                            // [884][4] k=0..3
    float* panB = lds + 3536;                     // [884][4] k=4..7
    float* panC = lds + 7072;                     // [884]    k=8
    const int c    = blockIdx.y;
    const int qb   = blockIdx.x;
    const int half = blockIdx.z;
    const int tid  = threadIdx.x;
    const float bmax = sqrtf(sumsq[0]);
    const float wmax = sqrtf(sumsq[1]);
    const float invb = 1.0f / bmax, invw = 1.0f / wmax;
    const float SC = 10.0f * 1.44269504088896f;   // SCALE * log2(e)

    // stage this half's pan keys into LDS
    const int lbase = half * LHALF;
    for (int ll = tid; ll < LHALF; ll += 512) {
        int l = lbase + ll;
        const float* src;
        int stride;
        float scale;
        if (l < L1V) {
            int i = l / 38, j = l - i * 38;
            src = base + c * HWV + i * 40 + j;
            stride = 40; scale = invb;
        } else {
            int l2 = l - L1V;
            int i = l2 / 18, j = l2 - i * 18;
            src = wf + c * 400 + i * 20 + j;
            stride = 20; scale = invw;
        }
        float v0 = src[0]          * scale, v1 = src[1]          * scale, v2 = src[2]          * scale;
        float v3 = src[stride]     * scale, v4 = src[stride+1]   * scale, v5 = src[stride+2]   * scale;
        float v6 = src[2*stride]   * scale, v7 = src[2*stride+1] * scale, v8 = src[2*stride+2] * scale;
        *reinterpret_cast<float4*>(&panA[ll*4]) = make_float4(v0, v1, v2, v3);
        *reinterpret_cast<float4*>(&panB[ll*4]) = make_float4(v4, v5, v6, v7);
        panC[ll] = v8;
    }

    // load Q=3 query vectors straight from global (overlaps with staging above),
    // pre-scaled by SCALE*log2(e)*norm
    const int lane = tid & 63;
    const int w    = tid >> 6;
    float q[3][9];
    #pragma unroll
    for (int qi = 0; qi < 3; ++qi) {
        int m = qb * 192 + qi * 64 + lane;         // < 1536 <= 1768, safe
        const float* src;
        int stride;
        float scale;
        if (m < L1V) {
            int i = m / 38, j = m - i * 38;
            src = base + c * HWV + i * 40 + j;
            stride = 40; scale = invb * SC;
        } else {
            int m2 = m - L1V;
            int i = m2 / 18, j = m2 - i * 18;
            src = wf + c * 400 + i * 20 + j;
            stride = 20; scale = invw * SC;
        }
        q[qi][0] = src[0]          * scale; q[qi][1] = src[1]          * scale; q[qi][2] = src[2]          * scale;
        q[qi][3] = src[stride]     * scale; q[qi][4] = src[stride+1]   * scale; q[qi][5] = src[stride+2]   * scale;
        q[qi][6] = src[2*stride]   * scale; q[qi][7] = src[2*stride+1] * scale; q[qi][8] = src[2*stride+2] * scale;
    }
    __syncthreads();

    float num[3][9];
    float den[3] = {0.f, 0.f, 0.f};
    #pragma unroll
    for (int qi = 0; qi < 3; ++qi)
        #pragma unroll
        for (int k = 0; k < 9; ++k) num[qi][k] = 0.f;

    // wave's key segment within the half: 884 = 8*110 + 4
    const int start = w * 110 + (w < 4 ? w : 4);
    const int end   = start + 110 + (w < 4 ? 1 : 0);
    const int B     = (half == 0) ? LHALF : LB1;   // base/wf boundary in local coords
    const int e1    = end < B ? end : B;
    const int s2    = start > B ? start : B;

    #define ATTN_ITER(VS)                                                     \
    {                                                                         \
        float4 A  = *reinterpret_cast<const float4*>(&panA[l*4]);             \
        float4 Bv = *reinterpret_cast<const float4*>(&panB[l*4]);             \
        float  c8 = panC[l];                                                  \
        _Pragma("unroll")                                                     \
        for (int qi = 0; qi < 3; ++qi) {                                      \
            float sA = q[qi][0]*A.x + q[qi][1]*A.y;                           \
            sA = sA + q[qi][2]*A.z;                                           \
            sA = sA + q[qi][3]*A.w;                                           \
            float sB = q[qi][8]*c8 + q[qi][4]*Bv.x;                           \
            sB = sB + q[qi][5]*Bv.y;                                          \
            sB = sB + q[qi][6]*Bv.z;                                          \
            sB = sB + q[qi][7]*Bv.w;                                          \
            float p  = __builtin_amdgcn_exp2f(sA + sB);                       \
            float pv = p * (VS);                                              \
            den[qi] += p;                                                     \
            num[qi][0] += pv*A.x;  num[qi][1] += pv*A.y;                      \
            num[qi][2] += pv*A.z;  num[qi][3] += pv*A.w;                      \
            num[qi][4] += pv*Bv.x; num[qi][5] += pv*Bv.y;                     \
            num[qi][6] += pv*Bv.z; num[qi][7] += pv*Bv.w;                     \
            num[qi][8] += pv*c8;                                              \
        }                                                                     \
    }

    for (int l = start; l < e1; ++l) ATTN_ITER(bmax)
    for (int l = s2;    l < end; ++l) ATTN_ITER(wmax)
    #undef ATTN_ITER

    __syncthreads();                 // pan no longer needed; overlay partials
    float* red = lds;                // [8 waves][192 q][10] = 61,440 B
    #pragma unroll
    for (int qi = 0; qi < 3; ++qi) {
        float* myp = red + (w * 192 + qi * 64 + lane) * 10;
        #pragma unroll
        for (int k = 0; k < 9; ++k) myp[k] = num[qi][k];
        myp[9] = den[qi];
    }
    __syncthreads();

    if (tid < 192) {
        float tot[10];
        #pragma unroll
        for (int j = 0; j < 10; ++j) {
            float s = 0.f;
            #pragma unroll
            for (int ww = 0; ww < 8; ++ww) s += red[(ww * 192 + tid) * 10 + j];
            tot[j] = s;
        }
        float* dst = part + ((size_t)(half * CRV + c) * 1536 + qb * 192 + tid) * 10;
        #pragma unroll
        for (int j = 0; j < 10; ++j) dst[j] = tot[j];
    }
}

// ---------------- K2b: merge key-halves, divide by den ----------------
__global__ __launch_bounds__(256) void k_comb(const float* __restrict__ part,
                                              float* __restrict__ patches)
{
    int t = blockIdx.x * 256 + threadIdx.x;
    if (t >= CRV * L1V) return;
    int c = t / L1V, m = t - c * L1V;
    const float* p0 = part + (size_t)c        * 15360 + m * 10;
    const float* p1 = part + (size_t)(CRV + c) * 15360 + m * 10;
    float tot[10];
    #pragma unroll
    for (int j = 0; j < 10; ++j) tot[j] = p0[j] + p1[j];
    float inv = 1.0f / tot[9];
    #pragma unroll
    for (int k = 0; k < 9; ++k)
        patches[(c * 9 + k) * L1V + m] = tot[k] * inv;
}

// ---------------- K3: fold (sum overlapping patches) / 9 ----------------
__global__ __launch_bounds__(256) void k_fold(const float* __restrict__ patches,
                                              float* __restrict__ folded)
{
    int t = blockIdx.x * 256 + threadIdx.x;
    if (t >= CRV * HWV) return;
    int c = t / HWV, px = t - c * HWV;
    int h = px / 40, w = px - h * 40;
    float acc = 0.f;
    #pragma unroll
    for (int di = 0; di < 3; ++di) {
        int i = h - di;
        if (i < 0 || i >= 38) continue;
        #pragma unroll
        for (int dj = 0; dj < 3; ++dj) {
            int j = w - dj;
            if (j < 0 || j >= 38) continue;
            acc += patches[(c * 9 + di * 3 + dj) * L1V + i * 38 + j];
        }
    }
    folded[t] = acc * (1.0f / 9.0f);
}

// ---------------- K4: y = prelu(w3·folded + b3) + x ----------------
__global__ __launch_bounds__(256) void k_out(const float* __restrict__ folded,
    const float* __restrict__ w3, const float* __restrict__ b3, const float* __restrict__ a3,
    const float* __restrict__ x, float* __restrict__ out)
{
    int t = blockIdx.x * 256 + threadIdx.x;
    if (t >= CHV * HWV) return;
    int oc = t / HWV, px = t - oc * HWV;
    float acc = b3[oc];
    #pragma unroll
    for (int ic = 0; ic < CRV; ++ic) acc += w3[oc * CRV + ic] * folded[ic * HWV + px];
    float a = a3[0];
    float v = acc >= 0.f ? acc : a * acc;
    out[t] = v + x[t];
}

extern "C" void kernel_launch(void* const* d_in, const int* in_sizes, int n_in,
                              void* d_out, int out_size, void* d_ws, size_t ws_size,
                              hipStream_t stream)
{
    const float* x  = (const float*)d_in[0];
    const float* w1 = (const float*)d_in[1];
    const float* b1 = (const float*)d_in[2];
    const float* a1 = (const float*)d_in[3];
    const float* w2 = (const float*)d_in[4];
    const float* b2 = (const float*)d_in[5];
    const float* a2 = (const float*)d_in[6];
    const float* w3 = (const float*)d_in[7];
    const float* b3 = (const float*)d_in[8];
    const float* a3 = (const float*)d_in[9];

    float* ws      = (float*)d_ws;
    float* sumsq   = ws;                               // 2 floats (+pad to 64)
    float* base    = ws + 64;                          // 32*1600 = 51200
    float* wfb     = base + CRV * HWV;                 // 32*400  = 12800
    float* patches = wfb + 12800;                      // 32*9*1444 = 415872
    float* folded  = patches + CRV * 9 * L1V;          // 51200
    float* part    = folded + CRV * HWV;               // 2*32*1536*10 = 983040 (~3.9 MB)

    hipMemsetAsync(sumsq, 0, 2 * sizeof(float), stream);
    k_front<<<250, 256, 0, stream>>>(x, w1, b1, a1, w2, b2, a2, base, wfb, sumsq);
    k_attn<<<dim3(8, 32, 2), 512, 0, stream>>>(base, wfb, sumsq, part);
    k_comb<<<181, 256, 0, stream>>>(part, patches);
    k_fold<<<200, 256, 0, stream>>>(patches, folded);
    k_out<<<400, 256, 0, stream>>>(folded, w3, b3, a3, x, (float*)d_out);
}